// Round 3
// baseline (2963.201 us; speedup 1.0000x reference)
//
#include <hip/hip_runtime.h>
#include <hip/hip_bf16.h>

typedef __attribute__((ext_vector_type(8))) short short8;
typedef __attribute__((ext_vector_type(4))) float f32x4;
typedef __attribute__((ext_vector_type(4))) unsigned int u32x4;

static constexpr int T = 512, B = 64, I = 512, H = 1024, O = 512;
static constexpr long TB = (long)T * B; // 32768

// ---------- bf16 helpers (RNE) ----------
__device__ __forceinline__ float bf2f(unsigned short h) {
  unsigned u = ((unsigned)h) << 16;
  return __builtin_bit_cast(float, u);
}
__device__ __forceinline__ unsigned short f2bf(float f) {
  unsigned u = __builtin_bit_cast(unsigned, f);
  u += 0x7fffu + ((u >> 16) & 1u);
  return (unsigned short)(u >> 16);
}

// ---------- MALL-direct (bypass L1+L2) ops ----------
__device__ __forceinline__ u32x4 load_sc(const void* p) {
  u32x4 v;
  asm volatile("global_load_dwordx4 %0, %1, off sc0 sc1" : "=v"(v) : "v"(p));
  return v;
}
__device__ __forceinline__ void store_sc_u32(void* p, unsigned int v) {
  asm volatile("global_store_dword %0, %1, off sc0 sc1" : : "v"(p), "v"(v) : "memory");
}
__device__ __forceinline__ void waitcnt_vm0() {
  asm volatile("s_waitcnt vmcnt(0)" ::: "memory");
}

// ---------- workspace layout (bytes) ----------
static constexpr size_t WS_WIH  = 0;                      // 1024*512  bf16 = 1 MB
static constexpr size_t WS_WHH  = WS_WIH + (1u << 20);    // 1024*1024 bf16 = 2 MB
static constexpr size_t WS_WFC  = WS_WHH + (2u << 20);    // 512*1024  bf16 = 1 MB
static constexpr size_t WS_RING = WS_WFC + (1u << 20);    // 4 * 64*1024 u32 = 1 MB
static constexpr size_t WS_XP   = WS_RING + (1u << 20);   // 32768*1024 bf16 = 64 MB
static constexpr size_t WS_HS   = WS_XP + (64u << 20);    // 32768*1024 bf16 = 64 MB
// total = 133 MB

// ---------- prep: weights fp32 -> bf16 ----------
__global__ void prep_kernel(const float* __restrict__ wih, const float* __restrict__ whh,
                            const float* __restrict__ wfc,
                            unsigned short* __restrict__ wih_bf, unsigned short* __restrict__ whh_bf,
                            unsigned short* __restrict__ wfc_bf) {
  long i = (long)blockIdx.x * blockDim.x + threadIdx.x;
  const long S1 = (long)H * I, S2 = (long)H * H, S3 = (long)O * H;
  if (i < S1) wih_bf[i] = f2bf(wih[i]);
  else if (i < S1 + S2) whh_bf[i - S1] = f2bf(whh[i - S1]);
  else if (i < S1 + S2 + S3) wfc_bf[i - S1 - S2] = f2bf(wfc[i - S1 - S2]);
}

// ---------- bulk GEMM: C[m,n] = sum_k A[m,k]*B[n,k] + bias0[n] (+ bias1[n]) ----------
// AMODE: 0 = A is bf16, 1 = A is fp32 (converted in staging).
template <int AMODE>
__global__ __launch_bounds__(256) void gemm_bt(const void* __restrict__ Av,
                                               const unsigned short* __restrict__ Bm,
                                               int M, int N, int K,
                                               const float* __restrict__ bias0,
                                               const float* __restrict__ bias1,
                                               float* __restrict__ Cf,
                                               unsigned short* __restrict__ Cb) {
  __shared__ __align__(16) unsigned short lA[128][40];
  __shared__ __align__(16) unsigned short lB[128][40];
  const int tid = threadIdx.x;
  const int wave = tid >> 6, lane = tid & 63;
  const int wm = (wave >> 1) * 64, wn = (wave & 1) * 64;
  const int lr = lane & 15, lq = lane >> 4;
  const long m0 = (long)blockIdx.y * 128, n0 = (long)blockIdx.x * 128;

  f32x4 acc[4][4];
#pragma unroll
  for (int i = 0; i < 4; ++i)
#pragma unroll
    for (int j = 0; j < 4; ++j) acc[i][j] = (f32x4){0.f, 0.f, 0.f, 0.f};

  const int srow = tid >> 2;
  const int scol = (tid & 3) * 8;
  const unsigned short* Agb = (const unsigned short*)Av + (m0 + srow) * K + scol;
  const float*          Agf = (const float*)Av + (m0 + srow) * K + scol;
  const unsigned short* Bg  = Bm + (n0 + srow) * K + scol;

  for (int k0 = 0; k0 < K; k0 += 32) {
    __syncthreads();
    if (AMODE == 0) {
      *(short8*)&lA[srow][scol]      = *(const short8*)(Agb + k0);
      *(short8*)&lA[srow + 64][scol] = *(const short8*)(Agb + 64L * K + k0);
    } else {
      f32x4 x0 = *(const f32x4*)(Agf + k0);
      f32x4 x1 = *(const f32x4*)(Agf + k0 + 4);
      f32x4 y0 = *(const f32x4*)(Agf + 64L * K + k0);
      f32x4 y1 = *(const f32x4*)(Agf + 64L * K + k0 + 4);
      short8 sa, sb;
#pragma unroll
      for (int j = 0; j < 4; ++j) {
        sa[j] = (short)f2bf(x0[j]); sa[j + 4] = (short)f2bf(x1[j]);
        sb[j] = (short)f2bf(y0[j]); sb[j + 4] = (short)f2bf(y1[j]);
      }
      *(short8*)&lA[srow][scol]      = sa;
      *(short8*)&lA[srow + 64][scol] = sb;
    }
    *(short8*)&lB[srow][scol]      = *(const short8*)(Bg + k0);
    *(short8*)&lB[srow + 64][scol] = *(const short8*)(Bg + 64L * K + k0);
    __syncthreads();
    short8 af[4], bf[4];
#pragma unroll
    for (int i = 0; i < 4; ++i) af[i] = *(const short8*)&lA[wm + i * 16 + lr][lq * 8];
#pragma unroll
    for (int j = 0; j < 4; ++j) bf[j] = *(const short8*)&lB[wn + j * 16 + lr][lq * 8];
#pragma unroll
    for (int i = 0; i < 4; ++i)
#pragma unroll
      for (int j = 0; j < 4; ++j)
        acc[i][j] = __builtin_amdgcn_mfma_f32_16x16x32_bf16(af[i], bf[j], acc[i][j], 0, 0, 0);
  }

#pragma unroll
  for (int j = 0; j < 4; ++j) {
    const long n = n0 + wn + j * 16 + lr;
    float bv = bias0[n] + (bias1 ? bias1[n] : 0.f);
#pragma unroll
    for (int i = 0; i < 4; ++i) {
#pragma unroll
      for (int r = 0; r < 4; ++r) {
        const long m = m0 + wm + i * 16 + lq * 4 + r;
        const float v = acc[i][j][r] + bv;
        if (Cb) Cb[m * N + n] = f2bf(v);
        else    Cf[m * N + n] = v;
      }
    }
  }
}

// ---------- recurrence v3: data-as-flag tagged ring, no barriers ----------
// 4 batch groups x 16 N-slice WGs. Writer at step t stores u32 (bf16<<16 | t+1)
// into ring slot t&3 (sc0sc1). Readers at step t poll slot (t-1)&3 for tag==t;
// payload arrives with the successful poll. Frag-linear LDS: zero bank conflicts.
__global__ __launch_bounds__(256, 1) void rnn_scan3(const unsigned short* __restrict__ xp,
                                                    const unsigned short* __restrict__ whh,
                                                    unsigned int* __restrict__ ring,
                                                    unsigned short* __restrict__ hs) {
  const int tid = threadIdx.x;
  const int wave = tid >> 6, lane = tid & 63;
  const int lr = lane & 15, lq = lane >> 4;
  const int g = blockIdx.x >> 4;
  const int s = blockIdx.x & 15;
  const int n0 = s * 64 + wave * 16;
  const int b0 = g * 16;

  // frag-linear: 16B block bn = (k/8)*16 + m  (m = batch row 0..15, k = 0..1023)
  __shared__ __align__(16) unsigned short hsh[2048 * 8]; // 32 KB

  // W_hh fragments: B[k][n], n = n0+lr, k = ks*32 + lq*8 + j
  short8 bfrag[32];
  {
    const unsigned short* wrow = whh + (long)(n0 + lr) * H + lq * 8;
#pragma unroll
    for (int ks = 0; ks < 32; ++ks) bfrag[ks] = *(const short8*)(wrow + ks * 32);
  }

  // per-thread staging offsets: bn_i = tid + i*256 → global u32 offset in a slot
  int goff[8];
#pragma unroll
  for (int i = 0; i < 8; ++i) {
    const int bn = tid + i * 256;
    goff[i] = (b0 + (bn & 15)) * H + (bn >> 4) * 8;
  }

  for (int t = 0; t < T; ++t) {
    // xp prefetch (cached; overlaps the poll)
    float xpv[4];
#pragma unroll
    for (int r = 0; r < 4; ++r)
      xpv[r] = bf2f(xp[(long)t * (B * H) + (long)(b0 + lq * 4 + r) * H + n0 + lr]);

    float hv[4] = {0.f, 0.f, 0.f, 0.f};
    if (t > 0) {
      const unsigned tag = (unsigned)t;
      const unsigned int* slot = ring + ((t - 1) & 3) * (B * H);
      u32x4 lo[8], hi[8];
      for (;;) {
#pragma unroll
        for (int i = 0; i < 8; ++i) {
          lo[i] = load_sc(slot + goff[i]);
          hi[i] = load_sc(slot + goff[i] + 4);
        }
        waitcnt_vm0();
        bool ok = true;
#pragma unroll
        for (int i = 0; i < 8; ++i) {
          ok &= ((lo[i].x & 0xffffu) == tag) & ((lo[i].y & 0xffffu) == tag) &
                ((lo[i].z & 0xffffu) == tag) & ((lo[i].w & 0xffffu) == tag);
          ok &= ((hi[i].x & 0xffffu) == tag) & ((hi[i].y & 0xffffu) == tag) &
                ((hi[i].z & 0xffffu) == tag) & ((hi[i].w & 0xffffu) == tag);
        }
        if (__all(ok)) break;
        __builtin_amdgcn_s_sleep(1);
      }
      __syncthreads();  // all waves done reading LDS from step t-1
#pragma unroll
      for (int i = 0; i < 8; ++i) {
        short8 sv;
#pragma unroll
        for (int j = 0; j < 4; ++j) {
          sv[j]     = (short)(((unsigned*)&lo[i])[j] >> 16);
          sv[j + 4] = (short)(((unsigned*)&hi[i])[j] >> 16);
        }
        *(short8*)&hsh[(tid + i * 256) * 8] = sv;
      }
      __syncthreads();  // staged data visible
      // MFMA over K=1024: frag addr = ks*512 + lq*128 + lr*8 (shorts) — linear per wave
      f32x4 a0 = (f32x4){0.f,0.f,0.f,0.f}, a1 = a0, a2 = a0, a3 = a0;
#pragma unroll
      for (int ks = 0; ks < 32; ks += 4) {
        short8 f0 = *(const short8*)&hsh[(ks + 0) * 512 + lq * 128 + lr * 8];
        short8 f1 = *(const short8*)&hsh[(ks + 1) * 512 + lq * 128 + lr * 8];
        short8 f2 = *(const short8*)&hsh[(ks + 2) * 512 + lq * 128 + lr * 8];
        short8 f3 = *(const short8*)&hsh[(ks + 3) * 512 + lq * 128 + lr * 8];
        a0 = __builtin_amdgcn_mfma_f32_16x16x32_bf16(f0, bfrag[ks + 0], a0, 0, 0, 0);
        a1 = __builtin_amdgcn_mfma_f32_16x16x32_bf16(f1, bfrag[ks + 1], a1, 0, 0, 0);
        a2 = __builtin_amdgcn_mfma_f32_16x16x32_bf16(f2, bfrag[ks + 2], a2, 0, 0, 0);
        a3 = __builtin_amdgcn_mfma_f32_16x16x32_bf16(f3, bfrag[ks + 3], a3, 0, 0, 0);
      }
#pragma unroll
      for (int r = 0; r < 4; ++r) hv[r] = (a0[r] + a1[r]) + (a2[r] + a3[r]);
    }
    // h_t = tanh(pre); tagged ring store (exchange) + plain store (for fc GEMM)
    unsigned int* wslot = ring + (t & 3) * (B * H);
#pragma unroll
    for (int r = 0; r < 4; ++r) {
      const int b = b0 + lq * 4 + r;
      const long off = (long)b * H + n0 + lr;
      const unsigned short hb = f2bf(tanhf(hv[r] + xpv[r]));
      store_sc_u32(wslot + off, ((unsigned)hb << 16) | (unsigned)(t + 1));
      hs[(long)t * (B * H) + off] = hb;
    }
  }
}

extern "C" void kernel_launch(void* const* d_in, const int* in_sizes, int n_in,
                              void* d_out, int out_size, void* d_ws, size_t ws_size,
                              hipStream_t stream) {
  const float* seq  = (const float*)d_in[0];
  const float* Wih  = (const float*)d_in[1];
  const float* Whh  = (const float*)d_in[2];
  const float* b_ih = (const float*)d_in[3];
  const float* b_hh = (const float*)d_in[4];
  const float* Wfc  = (const float*)d_in[5];
  const float* b_fc = (const float*)d_in[6];
  float* out = (float*)d_out;

  char* ws = (char*)d_ws;
  unsigned short* wih_bf = (unsigned short*)(ws + WS_WIH);
  unsigned short* whh_bf = (unsigned short*)(ws + WS_WHH);
  unsigned short* wfc_bf = (unsigned short*)(ws + WS_WFC);
  unsigned int*   ring   = (unsigned int*)(ws + WS_RING);
  unsigned short* xp_bf  = (unsigned short*)(ws + WS_XP);
  unsigned short* hs_bf  = (unsigned short*)(ws + WS_HS);

  // tag 0 never matches tags 1..512 (also robust if first call isn't poisoned)
  hipMemsetAsync(ring, 0, (1u << 20), stream);

  {
    const long total = (long)H * I + (long)H * H + (long)O * H;
    const int blocks = (int)((total + 255) / 256);
    prep_kernel<<<blocks, 256, 0, stream>>>(Wih, Whh, Wfc, wih_bf, whh_bf, wfc_bf);
  }

  { // x_proj = seq @ W_ih^T + b_ih + b_hh  (A fp32 converted in staging)
    dim3 grid(H / 128, TB / 128);
    gemm_bt<1><<<grid, 256, 0, stream>>>(seq, wih_bf, (int)TB, H, I, b_ih, b_hh, nullptr, xp_bf);
  }

  rnn_scan3<<<64, 256, 0, stream>>>(xp_bf, whh_bf, ring, hs_bf);

  { // out = hs @ W_fc^T + b_fc
    dim3 grid(O / 128, TB / 128);
    gemm_bt<0><<<grid, 256, 0, stream>>>(hs_bf, wfc_bf, (int)TB, O, H, b_fc, nullptr, out, nullptr);
  }
}

// Round 4
// 2685.755 us; speedup vs baseline: 1.1033x; 1.1033x over previous
//
#include <hip/hip_runtime.h>
#include <hip/hip_bf16.h>

typedef __attribute__((ext_vector_type(8))) short short8;
typedef __attribute__((ext_vector_type(4))) float f32x4;
typedef __attribute__((ext_vector_type(4))) unsigned int u32x4;

static constexpr int T = 512, B = 64, I = 512, H = 1024, O = 512;
static constexpr long TB = (long)T * B;   // 32768
static constexpr int BH = B * H;          // 65536

// ---------- bf16 helpers (RNE) ----------
__device__ __forceinline__ float bf2f(unsigned short h) {
  unsigned u = ((unsigned)h) << 16;
  return __builtin_bit_cast(float, u);
}
__device__ __forceinline__ unsigned short f2bf(float f) {
  unsigned u = __builtin_bit_cast(unsigned, f);
  u += 0x7fffu + ((u >> 16) & 1u);
  return (unsigned short)(u >> 16);
}

// ---------- MALL-direct (bypass L1+L2) ops ----------
#define PLOAD(dst, p, o) \
  asm volatile("global_load_dwordx4 %0, %1, off offset:" #o " sc0 sc1" \
               : "=v"(dst) : "v"(p))
__device__ __forceinline__ void store_sc_u32(void* p, unsigned int v) {
  asm volatile("global_store_dword %0, %1, off sc0 sc1" : : "v"(p), "v"(v) : "memory");
}
__device__ __forceinline__ void waitcnt_vm0() {
  asm volatile("s_waitcnt vmcnt(0)" ::: "memory");
}

// fast tanh: 1 - 2/(e^{2x}+1); exact saturation at +/-inf of exp
__device__ __forceinline__ float fast_tanh(float x) {
  float e = __expf(2.f * x);
  return 1.f - 2.f * __builtin_amdgcn_rcpf(e + 1.f);
}

// ---------- workspace layout (bytes) ----------
static constexpr size_t WS_WIH = 0;                       // 1024*512  bf16 = 1 MB
static constexpr size_t WS_WHH = WS_WIH + (1u << 20);     // 1024*1024 bf16 = 2 MB
static constexpr size_t WS_WFC = WS_WHH + (2u << 20);     // 512*1024  bf16 = 1 MB
static constexpr size_t WS_XP  = WS_WFC + (1u << 20);     // 32768*1024 bf16 = 64 MB
static constexpr size_t WS_HST = WS_XP + (64u << 20);     // 32768*1024 u32  = 128 MB (tagged h)
// total = 196 MB

// ---------- prep: weights fp32 -> bf16 ----------
__global__ void prep_kernel(const float* __restrict__ wih, const float* __restrict__ whh,
                            const float* __restrict__ wfc,
                            unsigned short* __restrict__ wih_bf, unsigned short* __restrict__ whh_bf,
                            unsigned short* __restrict__ wfc_bf) {
  long i = (long)blockIdx.x * blockDim.x + threadIdx.x;
  const long S1 = (long)H * I, S2 = (long)H * H, S3 = (long)O * H;
  if (i < S1) wih_bf[i] = f2bf(wih[i]);
  else if (i < S1 + S2) whh_bf[i - S1] = f2bf(whh[i - S1]);
  else if (i < S1 + S2 + S3) wfc_bf[i - S1 - S2] = f2bf(wfc[i - S1 - S2]);
}

// ---------- bulk GEMM: C[m,n] = sum_k A[m,k]*B[n,k] + bias0[n] (+ bias1[n]) ----------
// AMODE: 0 = A bf16, 1 = A fp32 (convert in staging), 2 = A tagged u32 (bf16 in high16)
template <int AMODE>
__global__ __launch_bounds__(256) void gemm_bt(const void* __restrict__ Av,
                                               const unsigned short* __restrict__ Bm,
                                               int M, int N, int K,
                                               const float* __restrict__ bias0,
                                               const float* __restrict__ bias1,
                                               float* __restrict__ Cf,
                                               unsigned short* __restrict__ Cb) {
  __shared__ __align__(16) unsigned short lA[128][40];
  __shared__ __align__(16) unsigned short lB[128][40];
  const int tid = threadIdx.x;
  const int wave = tid >> 6, lane = tid & 63;
  const int wm = (wave >> 1) * 64, wn = (wave & 1) * 64;
  const int lr = lane & 15, lq = lane >> 4;
  const long m0 = (long)blockIdx.y * 128, n0 = (long)blockIdx.x * 128;

  f32x4 acc[4][4];
#pragma unroll
  for (int i = 0; i < 4; ++i)
#pragma unroll
    for (int j = 0; j < 4; ++j) acc[i][j] = (f32x4){0.f, 0.f, 0.f, 0.f};

  const int srow = tid >> 2;
  const int scol = (tid & 3) * 8;
  const unsigned short* Agb = (const unsigned short*)Av + (m0 + srow) * K + scol;
  const float*          Agf = (const float*)Av + (m0 + srow) * K + scol;
  const unsigned*       Agu = (const unsigned*)Av + (m0 + srow) * K + scol;
  const unsigned short* Bg  = Bm + (n0 + srow) * K + scol;

  for (int k0 = 0; k0 < K; k0 += 32) {
    __syncthreads();
    if (AMODE == 0) {
      *(short8*)&lA[srow][scol]      = *(const short8*)(Agb + k0);
      *(short8*)&lA[srow + 64][scol] = *(const short8*)(Agb + 64L * K + k0);
    } else if (AMODE == 1) {
      f32x4 x0 = *(const f32x4*)(Agf + k0);
      f32x4 x1 = *(const f32x4*)(Agf + k0 + 4);
      f32x4 y0 = *(const f32x4*)(Agf + 64L * K + k0);
      f32x4 y1 = *(const f32x4*)(Agf + 64L * K + k0 + 4);
      short8 sa, sb;
#pragma unroll
      for (int j = 0; j < 4; ++j) {
        sa[j] = (short)f2bf(x0[j]); sa[j + 4] = (short)f2bf(x1[j]);
        sb[j] = (short)f2bf(y0[j]); sb[j + 4] = (short)f2bf(y1[j]);
      }
      *(short8*)&lA[srow][scol]      = sa;
      *(short8*)&lA[srow + 64][scol] = sb;
    } else {
      u32x4 x0 = *(const u32x4*)(Agu + k0);
      u32x4 x1 = *(const u32x4*)(Agu + k0 + 4);
      u32x4 y0 = *(const u32x4*)(Agu + 64L * K + k0);
      u32x4 y1 = *(const u32x4*)(Agu + 64L * K + k0 + 4);
      short8 sa, sb;
#pragma unroll
      for (int j = 0; j < 4; ++j) {
        sa[j] = (short)(x0[j] >> 16); sa[j + 4] = (short)(x1[j] >> 16);
        sb[j] = (short)(y0[j] >> 16); sb[j + 4] = (short)(y1[j] >> 16);
      }
      *(short8*)&lA[srow][scol]      = sa;
      *(short8*)&lA[srow + 64][scol] = sb;
    }
    *(short8*)&lB[srow][scol]      = *(const short8*)(Bg + k0);
    *(short8*)&lB[srow + 64][scol] = *(const short8*)(Bg + 64L * K + k0);
    __syncthreads();
    short8 af[4], bf[4];
#pragma unroll
    for (int i = 0; i < 4; ++i) af[i] = *(const short8*)&lA[wm + i * 16 + lr][lq * 8];
#pragma unroll
    for (int j = 0; j < 4; ++j) bf[j] = *(const short8*)&lB[wn + j * 16 + lr][lq * 8];
#pragma unroll
    for (int i = 0; i < 4; ++i)
#pragma unroll
      for (int j = 0; j < 4; ++j)
        acc[i][j] = __builtin_amdgcn_mfma_f32_16x16x32_bf16(af[i], bf[j], acc[i][j], 0, 0, 0);
  }

#pragma unroll
  for (int j = 0; j < 4; ++j) {
    const long n = n0 + wn + j * 16 + lr;
    float bv = bias0[n] + (bias1 ? bias1[n] : 0.f);
#pragma unroll
    for (int i = 0; i < 4; ++i) {
#pragma unroll
      for (int r = 0; r < 4; ++r) {
        const long m = m0 + wm + i * 16 + lq * 4 + r;
        const float v = acc[i][j][r] + bv;
        if (Cb) Cb[m * N + n] = f2bf(v);
        else    Cf[m * N + n] = v;
      }
    }
  }
}

// ---------- recurrence v4: K-split waves + fragment-direct tagged poll ----------
// 4 batch groups (16 rows) x 16 N-slice WGs (64 cols). Wave w of a WG reduces
// k in [w*256, w*256+256) for all 64 cols; lanes poll their own A-fragment
// words (tagged u32 = bf16<<16 | t+1) straight into MFMA layout. Cross-wave
// f32 partial reduce in LDS; tanh + tagged store by column owner.
__global__ __launch_bounds__(256, 1) void rnn_scan4(const unsigned short* __restrict__ xp,
                                                    const unsigned short* __restrict__ whh,
                                                    unsigned int* __restrict__ hst) {
  const int tid = threadIdx.x;
  const int wv = tid >> 6, lane = tid & 63;
  const int lr = lane & 15, lq = lane >> 4;
  const int g = blockIdx.x >> 4;
  const int s = blockIdx.x & 15;
  const int b0 = g * 16;
  const int n0own = s * 64 + wv * 16;   // columns this wave stores

  __shared__ float pbuf[4][16][65];     // [wave][row][col(+pad)] f32 partials

  // B fragments: bfrag[c][kt] -> B[k][n], n = s*64 + c*16 + lr, k = wv*256 + kt*32 + lq*8 + j
  short8 bfrag[4][8];
#pragma unroll
  for (int c = 0; c < 4; ++c) {
    const unsigned short* wrow = whh + (long)(s * 64 + c * 16 + lr) * H + wv * 256 + lq * 8;
#pragma unroll
    for (int kt = 0; kt < 8; ++kt) bfrag[c][kt] = *(const short8*)(wrow + kt * 32);
  }

  for (int t = 0; t < T; ++t) {
    // xp prefetch for owned cols (cached; overlaps poll)
    float xpv[4];
#pragma unroll
    for (int r = 0; r < 4; ++r)
      xpv[r] = bf2f(xp[(long)t * BH + (long)(b0 + lq * 4 + r) * H + n0own + lr]);

    f32x4 acc[4];
#pragma unroll
    for (int c = 0; c < 4; ++c) acc[c] = (f32x4){0.f, 0.f, 0.f, 0.f};

    if (t > 0) {
      const unsigned tag = (unsigned)t;
      // per-lane fragment base: row b0+lr, k = wv*256 + lq*8
      const unsigned* base = hst + (long)(t - 1) * BH + (long)(b0 + lr) * H + wv * 256 + lq * 8;
      u32x4 lo[8], hi[8];
      for (;;) {
        PLOAD(lo[0], base, 0);   PLOAD(hi[0], base, 16);
        PLOAD(lo[1], base, 128); PLOAD(hi[1], base, 144);
        PLOAD(lo[2], base, 256); PLOAD(hi[2], base, 272);
        PLOAD(lo[3], base, 384); PLOAD(hi[3], base, 400);
        PLOAD(lo[4], base, 512); PLOAD(hi[4], base, 528);
        PLOAD(lo[5], base, 640); PLOAD(hi[5], base, 656);
        PLOAD(lo[6], base, 768); PLOAD(hi[6], base, 784);
        PLOAD(lo[7], base, 896); PLOAD(hi[7], base, 912);
        waitcnt_vm0();
        unsigned bad = 0;
#pragma unroll
        for (int kt = 0; kt < 8; ++kt)
#pragma unroll
          for (int j = 0; j < 4; ++j) {
            bad |= (lo[kt][j] ^ tag) & 0xffffu;
            bad |= (hi[kt][j] ^ tag) & 0xffffu;
          }
        if (__all(bad == 0)) break;
        __builtin_amdgcn_s_sleep(1);
      }
      // fragments already in A layout: convert and multiply
#pragma unroll
      for (int kt = 0; kt < 8; ++kt) {
        short8 a;
#pragma unroll
        for (int j = 0; j < 4; ++j) {
          a[j]     = (short)(lo[kt][j] >> 16);
          a[j + 4] = (short)(hi[kt][j] >> 16);
        }
        acc[0] = __builtin_amdgcn_mfma_f32_16x16x32_bf16(a, bfrag[0][kt], acc[0], 0, 0, 0);
        acc[1] = __builtin_amdgcn_mfma_f32_16x16x32_bf16(a, bfrag[1][kt], acc[1], 0, 0, 0);
        acc[2] = __builtin_amdgcn_mfma_f32_16x16x32_bf16(a, bfrag[2][kt], acc[2], 0, 0, 0);
        acc[3] = __builtin_amdgcn_mfma_f32_16x16x32_bf16(a, bfrag[3][kt], acc[3], 0, 0, 0);
      }
    }

    __syncthreads();   // pbuf free (previous step's readers are done)
#pragma unroll
    for (int c = 0; c < 4; ++c)
#pragma unroll
      for (int r = 0; r < 4; ++r)
        pbuf[wv][lq * 4 + r][c * 16 + lr] = acc[c][r];
    __syncthreads();   // partials visible

    unsigned int* dst = hst + (long)t * BH + (long)(b0 + lq * 4) * H + n0own + lr;
#pragma unroll
    for (int r = 0; r < 4; ++r) {
      float sum = pbuf[0][lq * 4 + r][wv * 16 + lr] + pbuf[1][lq * 4 + r][wv * 16 + lr] +
                  pbuf[2][lq * 4 + r][wv * 16 + lr] + pbuf[3][lq * 4 + r][wv * 16 + lr];
      const unsigned short hb = f2bf(fast_tanh(sum + xpv[r]));
      store_sc_u32(dst + (long)r * H, ((unsigned)hb << 16) | (unsigned)(t + 1));
    }
  }
}

extern "C" void kernel_launch(void* const* d_in, const int* in_sizes, int n_in,
                              void* d_out, int out_size, void* d_ws, size_t ws_size,
                              hipStream_t stream) {
  const float* seq  = (const float*)d_in[0];
  const float* Wih  = (const float*)d_in[1];
  const float* Whh  = (const float*)d_in[2];
  const float* b_ih = (const float*)d_in[3];
  const float* b_hh = (const float*)d_in[4];
  const float* Wfc  = (const float*)d_in[5];
  const float* b_fc = (const float*)d_in[6];
  float* out = (float*)d_out;

  char* ws = (char*)d_ws;
  unsigned short* wih_bf = (unsigned short*)(ws + WS_WIH);
  unsigned short* whh_bf = (unsigned short*)(ws + WS_WHH);
  unsigned short* wfc_bf = (unsigned short*)(ws + WS_WFC);
  unsigned short* xp_bf  = (unsigned short*)(ws + WS_XP);
  unsigned int*   hst    = (unsigned int*)(ws + WS_HST);

  // no memset needed: harness 0xAA-poisons d_ws before every launch, and
  // tag 0xAAAA never matches tags 1..512.

  {
    const long total = (long)H * I + (long)H * H + (long)O * H;
    const int blocks = (int)((total + 255) / 256);
    prep_kernel<<<blocks, 256, 0, stream>>>(Wih, Whh, Wfc, wih_bf, whh_bf, wfc_bf);
  }

  { // x_proj = seq @ W_ih^T + b_ih + b_hh  (A fp32 converted in staging)
    dim3 grid(H / 128, TB / 128);
    gemm_bt<1><<<grid, 256, 0, stream>>>(seq, wih_bf, (int)TB, H, I, b_ih, b_hh, nullptr, xp_bf);
  }

  rnn_scan4<<<64, 256, 0, stream>>>(xp_bf, whh_bf, hst);

  { // out = hs @ W_fc^T + b_fc  (A = tagged u32, un-tag in staging)
    dim3 grid(O / 128, TB / 128);
    gemm_bt<2><<<grid, 256, 0, stream>>>(hst, wfc_bf, (int)TB, O, H, b_fc, nullptr, out, nullptr);
  }
}

// Round 5
// 2102.266 us; speedup vs baseline: 1.4095x; 1.2776x over previous
//
#include <hip/hip_runtime.h>
#include <hip/hip_bf16.h>

typedef __attribute__((ext_vector_type(8))) short short8;
typedef __attribute__((ext_vector_type(4))) float f32x4;
typedef __attribute__((ext_vector_type(4))) int i32x4;

static constexpr int T = 512, B = 64, I = 512, H = 1024, O = 512;
static constexpr long TB = (long)T * B;   // 32768
static constexpr int BH = B * H;          // 65536

// ---------- bf16 helpers (RNE) ----------
__device__ __forceinline__ float bf2f(unsigned short h) {
  unsigned u = ((unsigned)h) << 16;
  return __builtin_bit_cast(float, u);
}
__device__ __forceinline__ unsigned short f2bf(float f) {
  unsigned u = __builtin_bit_cast(unsigned, f);
  u += 0x7fffu + ((u >> 16) & 1u);
  return (unsigned short)(u >> 16);
}

// ---------- MALL-direct (bypass L1+L2) ops — used ONLY for flags + h stores ----------
__device__ __forceinline__ i32x4 load_flags_sc(const int* p) {
  i32x4 v;
  asm volatile("global_load_dwordx4 %0, %1, off sc0 sc1" : "=v"(v) : "v"(p) : "memory");
  return v;
}
__device__ __forceinline__ void store_sc_u16(void* p, unsigned int v) {
  asm volatile("global_store_short %0, %1, off sc0 sc1" : : "v"(p), "v"(v) : "memory");
}
__device__ __forceinline__ void store_sc_i32(int* p, int v) {
  asm volatile("global_store_dword %0, %1, off sc0 sc1" : : "v"(p), "v"(v) : "memory");
}
__device__ __forceinline__ void waitcnt_vm0() {
  asm volatile("s_waitcnt vmcnt(0)" ::: "memory");
}

// fast tanh: 1 - 2/(e^{2x}+1)
__device__ __forceinline__ float fast_tanh(float x) {
  float e = __expf(2.f * x);
  return 1.f - 2.f * __builtin_amdgcn_rcpf(e + 1.f);
}

// ---------- workspace layout (bytes) ----------
static constexpr size_t WS_WIH = 0;                     // 1024*512  bf16 = 1 MB
static constexpr size_t WS_WHH = (1u << 20);            // 1024*1024 bf16 = 2 MB
static constexpr size_t WS_WFC = (3u << 20);            // 512*1024  bf16 = 1 MB
static constexpr size_t WS_FLG = (4u << 20);            // 64 ints (+pad)
static constexpr size_t WS_XP  = (5u << 20);            // 32768*1024 bf16 = 64 MB
static constexpr size_t WS_HS  = WS_XP + (64u << 20);   // 32768*1024 bf16 = 64 MB
// total = 133 MB

// ---------- prep: weights fp32 -> bf16 ----------
__global__ void prep_kernel(const float* __restrict__ wih, const float* __restrict__ whh,
                            const float* __restrict__ wfc,
                            unsigned short* __restrict__ wih_bf, unsigned short* __restrict__ whh_bf,
                            unsigned short* __restrict__ wfc_bf) {
  long i = (long)blockIdx.x * blockDim.x + threadIdx.x;
  const long S1 = (long)H * I, S2 = (long)H * H, S3 = (long)O * H;
  if (i < S1) wih_bf[i] = f2bf(wih[i]);
  else if (i < S1 + S2) whh_bf[i - S1] = f2bf(whh[i - S1]);
  else if (i < S1 + S2 + S3) wfc_bf[i - S1 - S2] = f2bf(wfc[i - S1 - S2]);
}

// ---------- bulk GEMM: C[m,n] = sum_k A[m,k]*B[n,k] + bias0[n] (+ bias1[n]) ----------
// AMODE: 0 = A bf16, 1 = A fp32 (convert in staging)
template <int AMODE>
__global__ __launch_bounds__(256) void gemm_bt(const void* __restrict__ Av,
                                               const unsigned short* __restrict__ Bm,
                                               int M, int N, int K,
                                               const float* __restrict__ bias0,
                                               const float* __restrict__ bias1,
                                               float* __restrict__ Cf,
                                               unsigned short* __restrict__ Cb) {
  __shared__ __align__(16) unsigned short lA[128][40];
  __shared__ __align__(16) unsigned short lB[128][40];
  const int tid = threadIdx.x;
  const int wave = tid >> 6, lane = tid & 63;
  const int wm = (wave >> 1) * 64, wn = (wave & 1) * 64;
  const int lr = lane & 15, lq = lane >> 4;
  const long m0 = (long)blockIdx.y * 128, n0 = (long)blockIdx.x * 128;

  f32x4 acc[4][4];
#pragma unroll
  for (int i = 0; i < 4; ++i)
#pragma unroll
    for (int j = 0; j < 4; ++j) acc[i][j] = (f32x4){0.f, 0.f, 0.f, 0.f};

  const int srow = tid >> 2;
  const int scol = (tid & 3) * 8;
  const unsigned short* Agb = (const unsigned short*)Av + (m0 + srow) * K + scol;
  const float*          Agf = (const float*)Av + (m0 + srow) * K + scol;
  const unsigned short* Bg  = Bm + (n0 + srow) * K + scol;

  for (int k0 = 0; k0 < K; k0 += 32) {
    __syncthreads();
    if (AMODE == 0) {
      *(short8*)&lA[srow][scol]      = *(const short8*)(Agb + k0);
      *(short8*)&lA[srow + 64][scol] = *(const short8*)(Agb + 64L * K + k0);
    } else {
      f32x4 x0 = *(const f32x4*)(Agf + k0);
      f32x4 x1 = *(const f32x4*)(Agf + k0 + 4);
      f32x4 y0 = *(const f32x4*)(Agf + 64L * K + k0);
      f32x4 y1 = *(const f32x4*)(Agf + 64L * K + k0 + 4);
      short8 sa, sb;
#pragma unroll
      for (int j = 0; j < 4; ++j) {
        sa[j] = (short)f2bf(x0[j]); sa[j + 4] = (short)f2bf(x1[j]);
        sb[j] = (short)f2bf(y0[j]); sb[j + 4] = (short)f2bf(y1[j]);
      }
      *(short8*)&lA[srow][scol]      = sa;
      *(short8*)&lA[srow + 64][scol] = sb;
    }
    *(short8*)&lB[srow][scol]      = *(const short8*)(Bg + k0);
    *(short8*)&lB[srow + 64][scol] = *(const short8*)(Bg + 64L * K + k0);
    __syncthreads();
    short8 af[4], bf[4];
#pragma unroll
    for (int i = 0; i < 4; ++i) af[i] = *(const short8*)&lA[wm + i * 16 + lr][lq * 8];
#pragma unroll
    for (int j = 0; j < 4; ++j) bf[j] = *(const short8*)&lB[wn + j * 16 + lr][lq * 8];
#pragma unroll
    for (int i = 0; i < 4; ++i)
#pragma unroll
      for (int j = 0; j < 4; ++j)
        acc[i][j] = __builtin_amdgcn_mfma_f32_16x16x32_bf16(af[i], bf[j], acc[i][j], 0, 0, 0);
  }

#pragma unroll
  for (int j = 0; j < 4; ++j) {
    const long n = n0 + wn + j * 16 + lr;
    float bv = bias0[n] + (bias1 ? bias1[n] : 0.f);
#pragma unroll
    for (int i = 0; i < 4; ++i) {
#pragma unroll
      for (int r = 0; r < 4; ++r) {
        const long m = m0 + wm + i * 16 + lq * 4 + r;
        const float v = acc[i][j][r] + bv;
        if (Cb) Cb[m * N + n] = f2bf(v);
        else    Cf[m * N + n] = v;
      }
    }
  }
}

// ---------- recurrence v5: flag-notified single-pull ----------
// 4 groups x 16 slices; g = blk&3 clusters a group's WGs on XCDs {g, g+4} so
// cached pulls of the (identical) 32KB h-frame share L2 ~8-way.
// Writers: store h (sc0sc1) -> vmcnt(0) -> barrier -> flag[g][s] = t+1 (sc0sc1).
// Reader wave wv polls flags of its 4 producers (one dwordx4, sc0sc1), then
// pulls its A-fragments with PLAIN CACHED loads (every hs address is first
// touched post-flag, so caches can never hold stale data).
__global__ __launch_bounds__(256, 1) void rnn_scan5(const unsigned short* __restrict__ xp,
                                                    const unsigned short* __restrict__ whh,
                                                    unsigned short* __restrict__ hs,
                                                    int* __restrict__ flags) {
  const int tid = threadIdx.x;
  const int wv = tid >> 6, lane = tid & 63;
  const int lr = lane & 15, lq = lane >> 4;
  const int g = blockIdx.x & 3;
  const int s = blockIdx.x >> 2;
  const int b0 = g * 16;

  __shared__ __align__(16) float pbuf[4 * 1024];  // [wv][c*256 + lane*4 + r], 16 KB

  // B fragments: bfrag[c][kt] -> B[k][n], n = s*64 + c*16 + lr, k = wv*256 + kt*32 + lq*8 + j
  short8 bfrag[4][8];
#pragma unroll
  for (int c = 0; c < 4; ++c) {
    const unsigned short* wrow = whh + (long)(s * 64 + c * 16 + lr) * H + wv * 256 + lq * 8;
#pragma unroll
    for (int kt = 0; kt < 8; ++kt) bfrag[c][kt] = *(const short8*)(wrow + kt * 32);
  }

  // reduce/store ownership of this thread: rows m = mrow+j (j=0..3), col ncol
  const int mrow = ((tid >> 4) & 3) * 4;
  const int ncol = s * 64 + (tid >> 6) * 16 + (tid & 15);
  const int* fptr = flags + g * 16 + wv * 4;   // this wave's 4 producers
  int* myflag = flags + g * 16 + s;

  for (int t = 0; t < T; ++t) {
    // xp prefetch (cached), at this thread's output coordinates
    float xpv[4];
#pragma unroll
    for (int j = 0; j < 4; ++j)
      xpv[j] = bf2f(xp[(long)t * BH + (long)(b0 + mrow + j) * H + ncol]);

    f32x4 acc[4];
#pragma unroll
    for (int c = 0; c < 4; ++c) acc[c] = (f32x4){0.f, 0.f, 0.f, 0.f};

    if (t > 0) {
      // cheap flag poll: all 4 producers must have published step t-1 (flag >= t).
      // signed compare: 0xAAAAAAAA poison and memset-0 both block.
      for (;;) {
        i32x4 f = load_flags_sc(fptr);
        waitcnt_vm0();
        if (f[0] >= t && f[1] >= t && f[2] >= t && f[3] >= t) break;
        __builtin_amdgcn_s_sleep(1);
      }
      // pull A-fragments: plain cached 16B loads, already in MFMA A layout
      const unsigned short* ab = hs + (long)(t - 1) * BH + (long)(b0 + lr) * H + wv * 256 + lq * 8;
      short8 af[8];
#pragma unroll
      for (int kt = 0; kt < 8; ++kt) af[kt] = *(const short8*)(ab + kt * 32);
#pragma unroll
      for (int kt = 0; kt < 8; ++kt) {
        acc[0] = __builtin_amdgcn_mfma_f32_16x16x32_bf16(af[kt], bfrag[0][kt], acc[0], 0, 0, 0);
        acc[1] = __builtin_amdgcn_mfma_f32_16x16x32_bf16(af[kt], bfrag[1][kt], acc[1], 0, 0, 0);
        acc[2] = __builtin_amdgcn_mfma_f32_16x16x32_bf16(af[kt], bfrag[2][kt], acc[2], 0, 0, 0);
        acc[3] = __builtin_amdgcn_mfma_f32_16x16x32_bf16(af[kt], bfrag[3][kt], acc[3], 0, 0, 0);
      }
    }

    // cross-wave K-reduce via fragment-linear LDS (conflict-free b128s)
#pragma unroll
    for (int c = 0; c < 4; ++c)
      *(f32x4*)&pbuf[wv * 1024 + c * 256 + lane * 4] = acc[c];
    __syncthreads();   // partials visible

    f32x4 p0 = *(const f32x4*)&pbuf[0 * 1024 + 4 * tid];
    f32x4 p1 = *(const f32x4*)&pbuf[1 * 1024 + 4 * tid];
    f32x4 p2 = *(const f32x4*)&pbuf[2 * 1024 + 4 * tid];
    f32x4 p3 = *(const f32x4*)&pbuf[3 * 1024 + 4 * tid];
    f32x4 sum = (p0 + p1) + (p2 + p3);

    unsigned short* dst = hs + (long)t * BH + (long)(b0 + mrow) * H + ncol;
#pragma unroll
    for (int j = 0; j < 4; ++j) {
      const unsigned short hb = f2bf(fast_tanh(sum[j] + xpv[j]));
      store_sc_u16(dst + (long)j * H, (unsigned int)hb);
    }
    waitcnt_vm0();       // my h stores ACKed at MALL
    __syncthreads();     // all 4 waves drained; also separates pbuf read/next write
    if (tid == 0) store_sc_i32(myflag, t + 1);
  }
}

extern "C" void kernel_launch(void* const* d_in, const int* in_sizes, int n_in,
                              void* d_out, int out_size, void* d_ws, size_t ws_size,
                              hipStream_t stream) {
  const float* seq  = (const float*)d_in[0];
  const float* Wih  = (const float*)d_in[1];
  const float* Whh  = (const float*)d_in[2];
  const float* b_ih = (const float*)d_in[3];
  const float* b_hh = (const float*)d_in[4];
  const float* Wfc  = (const float*)d_in[5];
  const float* b_fc = (const float*)d_in[6];
  float* out = (float*)d_out;

  char* ws = (char*)d_ws;
  unsigned short* wih_bf = (unsigned short*)(ws + WS_WIH);
  unsigned short* whh_bf = (unsigned short*)(ws + WS_WHH);
  unsigned short* wfc_bf = (unsigned short*)(ws + WS_WFC);
  int*            flags  = (int*)(ws + WS_FLG);
  unsigned short* xp_bf  = (unsigned short*)(ws + WS_XP);
  unsigned short* hs_bf  = (unsigned short*)(ws + WS_HS);

  // flags must start < 1 regardless of ws initial state
  hipMemsetAsync(flags, 0, 4096, stream);

  {
    const long total = (long)H * I + (long)H * H + (long)O * H;
    const int blocks = (int)((total + 255) / 256);
    prep_kernel<<<blocks, 256, 0, stream>>>(Wih, Whh, Wfc, wih_bf, whh_bf, wfc_bf);
  }

  { // x_proj = seq @ W_ih^T + b_ih + b_hh  (A fp32 converted in staging)
    dim3 grid(H / 128, TB / 128);
    gemm_bt<1><<<grid, 256, 0, stream>>>(seq, wih_bf, (int)TB, H, I, b_ih, b_hh, nullptr, xp_bf);
  }

  rnn_scan5<<<64, 256, 0, stream>>>(xp_bf, whh_bf, hs_bf, flags);

  { // out = hs @ W_fc^T + b_fc
    dim3 grid(O / 128, TB / 128);
    gemm_bt<0><<<grid, 256, 0, stream>>>(hs_bf, wfc_bf, (int)TB, O, H, b_fc, nullptr, out, nullptr);
  }
}